// Round 10
// baseline (87.162 us; speedup 1.0000x reference)
//
#include <hip/hip_runtime.h>
#include <math.h>

#define B_N 4096
#define L_N 16
#define NJC 128            // j-chunks (grid.y); 16 x 128 = 2048 blocks = 8/CU
#define CSTRIDE 48         // floats per j record: [0:16)=A [16:32)=B [32:48)=C

#define NHALF_LOG2E 0.7213475204444817f   // 0.5 * log2(e)
#define LOG2E_F     1.4426950408889634f
#define LN2_F       0.6931471805599453f
#define LOG_2PI_F   1.8378770664093453f

typedef float f32x2 __attribute__((ext_vector_type(2)));

// ws layout (floats):
//   coef : [B_N][CSTRIDE]    (768 KB, L2-resident)
//   part : [njc][17][B_N]    per-chunk partials (0..15 = per-l exp2 sums, 16 = sum2)
//   part2: [17][B_N]         chunk-summed

// ---- coefficients: logq2(i,j,l) = A*z^2 + B*z + C (log2 domain); also zero out ----
extern "C" __global__ __launch_bounds__(256)
void btc_coef(const float* __restrict__ zm, const float* __restrict__ zlv,
              float* __restrict__ coef, float* __restrict__ out) {
    const int g = blockIdx.x * 256 + threadIdx.x;   // 65536 = B_N * L_N
    if (g == 0) out[0] = 0.0f;                      // atomic target for btc_fin
    const int j = g >> 4, l = g & 15;
    float M  = zm[g];
    float lv = zlv[g];
    float A  = -NHALF_LOG2E * __builtin_amdgcn_exp2f(-LOG2E_F * lv);
    float Bc = -2.0f * A * M;
    float C  = fmaf(A, M * M, -NHALF_LOG2E * (lv + LOG_2PI_F));
    float* r = coef + (size_t)j * CSTRIDE;
    r[l] = A; r[16 + l] = Bc; r[32 + l] = C;
}

// ---- main: thread owns i; j-range block-uniform -> coefficients via s_load.
//      No LDS, no syncthreads: each thread writes its own partials. ----
extern "C" __global__ __launch_bounds__(256, 4)
void btc_main(const float* __restrict__ z, const float* __restrict__ coef,
              float* __restrict__ part, int jc /* j's per chunk */) {
    const int i  = blockIdx.x * 256 + threadIdx.x;
    const int jb = blockIdx.y * jc;                 // block-uniform (SGPR path)

    f32x2 z2[8], u2[8], acc[8];
    {
        const float4* zp = (const float4*)(z + (size_t)i * L_N);
        #pragma unroll
        for (int q = 0; q < 4; ++q) {
            float4 v = zp[q];
            z2[2*q]   = (f32x2){v.x, v.y};
            z2[2*q+1] = (f32x2){v.z, v.w};
        }
    }
    #pragma unroll
    for (int q = 0; q < 8; ++q) { u2[q] = z2[q] * z2[q]; acc[q] = (f32x2){0.f, 0.f}; }
    float sum2 = 0.0f;   // diag term keeps this > 0; no max tracking needed

    const float* cj = coef + (size_t)jb * CSTRIDE;
    for (int jj = 0; jj < jc; ++jj, cj += CSTRIDE) {
        f32x2 prod = (f32x2){1.f, 1.f};
        #pragma unroll
        for (int q = 0; q < 8; ++q) {
            // cj uniform -> s_load_dwordx16; each VOP3 reads exactly 1 scalar pair
            f32x2 Av = {cj[2*q],      cj[2*q + 1]};
            f32x2 Bv = {cj[16 + 2*q], cj[16 + 2*q + 1]};
            f32x2 Cv = {cj[32 + 2*q], cj[32 + 2*q + 1]};
            f32x2 t  = Bv * z2[q];          // v_pk_mul_f32 (1 sgpr)
            t        = Av * u2[q] + t;      // v_pk_fma_f32 (1 sgpr)
            f32x2 lg = t + Cv;              // v_pk_add_f32 (1 sgpr)
            f32x2 e  = (f32x2){__builtin_amdgcn_exp2f(lg.x),
                               __builtin_amdgcn_exp2f(lg.y)};
            acc[q] += e;
            prod   *= e;                    // exp2(sum_l lg) = prod_l exp2(lg)
        }
        sum2 += prod.x * prod.y;
    }

    float* base = part + (size_t)blockIdx.y * 17 * B_N + i;
    #pragma unroll
    for (int q = 0; q < 8; ++q) {
        base[(size_t)(2*q)     * B_N] = acc[q].x;
        base[(size_t)(2*q + 1) * B_N] = acc[q].y;
    }
    base[(size_t)16 * B_N] = sum2;
}

// ---- sum partials over chunks (wide grid, coalesced) ----
extern "C" __global__ __launch_bounds__(256)
void btc_sum(const float* __restrict__ part, float* __restrict__ part2, int njc) {
    const int g = blockIdx.x * 256 + threadIdx.x;   // 17*B_N elems
    float s = 0.0f;
    for (int c = 0; c < njc; ++c) s += part[(size_t)c * 17 * B_N + g];
    part2[g] = s;
}

// ---- finish per-i logs, global mean via one atomic per block ----
extern "C" __global__ __launch_bounds__(256)
void btc_fin(const float* __restrict__ part2, float* __restrict__ out) {
    const int tid = threadIdx.x;
    const int i   = blockIdx.x * 256 + tid;

    float lqprod2 = 0.0f;
    #pragma unroll
    for (int l = 0; l < L_N; ++l)
        lqprod2 += __builtin_amdgcn_logf(part2[(size_t)l * B_N + i]);
    float v = LN2_F * (__builtin_amdgcn_logf(part2[(size_t)16 * B_N + i]) - lqprod2);

    #pragma unroll
    for (int off = 32; off > 0; off >>= 1) v += __shfl_down(v, off);
    __shared__ float red[4];
    const int lane = tid & 63, w = tid >> 6;
    if (lane == 0) red[w] = v;
    __syncthreads();
    if (tid == 0)
        atomicAdd(out, ((red[0] + red[1]) + (red[2] + red[3])) * (1.0f / (float)B_N));
}

extern "C" void kernel_launch(void* const* d_in, const int* in_sizes, int n_in,
                              void* d_out, int out_size, void* d_ws, size_t ws_size,
                              hipStream_t stream) {
    const float* z   = (const float*)d_in[0];
    const float* zm  = (const float*)d_in[1];
    const float* zlv = (const float*)d_in[2];
    float* out  = (float*)d_out;
    float* coef = (float*)d_ws;
    float* part = coef + (size_t)B_N * CSTRIDE;

    int njc = NJC;
    while (njc > 1) {
        size_t need = ((size_t)B_N * CSTRIDE + (size_t)njc * 17 * B_N + 17 * B_N)
                      * sizeof(float);
        if (need <= ws_size) break;
        njc >>= 1;
    }
    const int jc = B_N / njc;
    float* part2 = part + (size_t)njc * 17 * B_N;

    hipLaunchKernelGGL(btc_coef, dim3(B_N * L_N / 256), dim3(256), 0, stream,
                       zm, zlv, coef, out);
    hipLaunchKernelGGL(btc_main, dim3(B_N / 256, njc), dim3(256), 0, stream,
                       z, coef, part, jc);
    hipLaunchKernelGGL(btc_sum, dim3(17 * B_N / 256), dim3(256), 0, stream,
                       part, part2, njc);
    hipLaunchKernelGGL(btc_fin, dim3(B_N / 256), dim3(256), 0, stream,
                       part2, out);
}